// Round 4
// baseline (96.860 us; speedup 1.0000x reference)
//
#include <hip/hip_runtime.h>

// Problem constants
#define B_  32
#define L_  2048
#define D_  256
#define T_  64
#define KW  3

typedef float f32x4 __attribute__((ext_vector_type(4)));
typedef short s16x8 __attribute__((ext_vector_type(8)));
typedef short s16x4 __attribute__((ext_vector_type(4)));

__device__ __forceinline__ short f2bf(float f) {
    unsigned u = __builtin_bit_cast(unsigned, f);
    u += 0x7FFFu + ((u >> 16) & 1u);          // round-to-nearest-even
    return (short)(u >> 16);
}

// ---------------------------------------------------------------------------
// prep A: CbfPk = bf16(C) packed in phase-1 B-fragment order:
//   value C[t][d] -> CbfPk[(((tt*8+ks)*4+g)*16 + c)*8 + e]
//   with tt=t>>4, c=t&15, ks=d>>5, g=(d>>3)&3, e=d&7
// ---------------------------------------------------------------------------
__global__ __launch_bounds__(256) void cbf_kernel(const float* __restrict__ C,
                                                  short* __restrict__ CbfPk) {
    const int i0 = (blockIdx.x * 256 + threadIdx.x) * 4;
    const int t = i0 >> 8, d = i0 & 255;
    const f32x4 v = *(const f32x4*)(C + i0);
    s16x4 s;
    s[0] = f2bf(v[0]); s[1] = f2bf(v[1]); s[2] = f2bf(v[2]); s[3] = f2bf(v[3]);
    const int tt = t >> 4, c = t & 15, ks = d >> 5, gg = (d >> 3) & 3, e = d & 7;
    *(s16x4*)&CbfPk[(((tt * 8 + ks) * 4 + gg) * 16 + c) * 8 + e] = s;
}

// ---------------------------------------------------------------------------
// prep B: kc[n][t] = relu(b[n] + sum_dd C[t][dd]*W[dd][n]) packed in phase-2
// B-fragment order: value (n,t) -> kcPk[(((nb*2+ks)*4+g)*16 + c)*8 + e]
//   nb=n>>4, c=n&15, ks=t>>5, g=(t>>3)&3, e=t&7
// grid 48 (nb = blockIdx.x covers 16 n), block 256 = 64 t x 4 nl
// ---------------------------------------------------------------------------
__global__ __launch_bounds__(256) void kc_prep(const float* __restrict__ C,
                                               const float* __restrict__ W,
                                               const float* __restrict__ bias,
                                               short* __restrict__ kcPk) {
    __shared__ float Ws[256 * 16];
    const int tid = threadIdx.x;
    const int n0  = blockIdx.x * 16;

    for (int idx = tid; idx < 256 * 16; idx += 256) {
        const int dd = idx >> 4, nl = idx & 15;
        Ws[idx] = W[dd * (KW * D_) + n0 + nl];
    }
    __syncthreads();

    const int t  = tid >> 2;
    const int nl = tid & 3;
    float acc[4];
    #pragma unroll
    for (int i = 0; i < 4; ++i) acc[i] = bias[n0 + nl + 4 * i];

    const float* Crow = C + t * D_;
    for (int dd = 0; dd < D_; ++dd) {
        const float cv = Crow[dd];
        #pragma unroll
        for (int i = 0; i < 4; ++i)
            acc[i] = fmaf(cv, Ws[dd * 16 + nl + 4 * i], acc[i]);
    }
    const int nb = blockIdx.x, ks = t >> 5, gg = (t >> 3) & 3, e = t & 7;
    #pragma unroll
    for (int i = 0; i < 4; ++i) {
        const int cc = nl + 4 * i;
        kcPk[(((nb * 2 + ks) * 4 + gg) * 16 + cc) * 8 + e] = f2bf(fmaxf(acc[i], 0.f));
    }
}

// ---------------------------------------------------------------------------
// main: per block = 64 rows of one batch, 4 waves, LDS = atts only (9 KB).
//  phase1: att[64][64] = x @ C^T via MFMA; A-frags straight from global x,
//          B-frags from packed CbfPk (wave-contiguous 1KB reads).
//  phase2: per wave: 4 d-tiles x 3 j x 4 M-tiles via MFMA (A=atts LDS,
//          B=kcPk packed); 3-tap window fold reads x from global (predicated),
//          fp32 store.
// ---------------------------------------------------------------------------
#define ATS 72

__global__ __launch_bounds__(256, 4) void main_kernel(const float* __restrict__ x,
                                                      const short* __restrict__ CbfPk,
                                                      const short* __restrict__ kcPk,
                                                      float* __restrict__ out) {
    __shared__ short atts[64 * ATS];    // 9216 B

    const int tid  = threadIdx.x;
    const int w    = tid >> 6;        // wave 0..3
    const int lane = tid & 63;
    const int c    = lane & 15;
    const int g    = lane >> 4;
    const int l0   = blockIdx.x * 64;
    const int b    = blockIdx.y;

    const float* xb = x + (size_t)b * L_ * D_;

    // ---- phase 1: wave w computes att rows [w*16, w*16+16) x all 64 t ----
    {
        f32x4 acc[4];
        #pragma unroll
        for (int tt = 0; tt < 4; ++tt) acc[tt] = (f32x4){0.f, 0.f, 0.f, 0.f};

        const float* xrow = xb + (size_t)(l0 + w * 16 + c) * D_;
        #pragma unroll
        for (int ks = 0; ks < 8; ++ks) {
            const f32x4 v0 = *(const f32x4*)(xrow + ks * 32 + g * 8);
            const f32x4 v1 = *(const f32x4*)(xrow + ks * 32 + g * 8 + 4);
            s16x8 a;
            a[0] = f2bf(v0[0]); a[1] = f2bf(v0[1]); a[2] = f2bf(v0[2]); a[3] = f2bf(v0[3]);
            a[4] = f2bf(v1[0]); a[5] = f2bf(v1[1]); a[6] = f2bf(v1[2]); a[7] = f2bf(v1[3]);
            #pragma unroll
            for (int tt = 0; tt < 4; ++tt) {
                const s16x8 bf = *(const s16x8*)&CbfPk[(((tt * 8 + ks) * 4 + g) * 16 + c) * 8];
                acc[tt] = __builtin_amdgcn_mfma_f32_16x16x32_bf16(a, bf, acc[tt], 0, 0, 0);
            }
        }
        // D layout: col=lane&15 (t), row=(lane>>4)*4+reg (l)
        #pragma unroll
        for (int tt = 0; tt < 4; ++tt)
            #pragma unroll
            for (int r = 0; r < 4; ++r)
                atts[(w * 16 + g * 4 + r) * ATS + tt * 16 + c] = f2bf(acc[tt][r]);
    }
    __syncthreads();

    // ---- phase 2 ----
    s16x8 afr[4][2];
    #pragma unroll
    for (int m = 0; m < 4; ++m)
        #pragma unroll
        for (int ks = 0; ks < 2; ++ks)
            afr[m][ks] = *(const s16x8*)&atts[(m * 16 + c) * ATS + ks * 32 + g * 8];

    const size_t outBase = ((size_t)b * L_ + l0) * D_;

    for (int dtl = 0; dtl < 4; ++dtl) {
        const int dcol    = w * 64 + dtl * 16 + c;
        const int nb_base = w * 4 + dtl;          // nb = j*16 + nb_base
        s16x8 bfr[3][2];
        #pragma unroll
        for (int j = 0; j < 3; ++j)
            #pragma unroll
            for (int ks = 0; ks < 2; ++ks)
                bfr[j][ks] = *(const s16x8*)&kcPk[((((j * 16 + nb_base) * 2 + ks) * 4 + g) * 16 + c) * 8];

        const float* xcol = xb + dcol;

        #pragma unroll
        for (int m = 0; m < 4; ++m) {
            f32x4 a0 = (f32x4){0.f,0.f,0.f,0.f};
            f32x4 a1 = (f32x4){0.f,0.f,0.f,0.f};
            f32x4 a2 = (f32x4){0.f,0.f,0.f,0.f};
            a0 = __builtin_amdgcn_mfma_f32_16x16x32_bf16(afr[m][0], bfr[0][0], a0, 0, 0, 0);
            a0 = __builtin_amdgcn_mfma_f32_16x16x32_bf16(afr[m][1], bfr[0][1], a0, 0, 0, 0);
            a1 = __builtin_amdgcn_mfma_f32_16x16x32_bf16(afr[m][0], bfr[1][0], a1, 0, 0, 0);
            a1 = __builtin_amdgcn_mfma_f32_16x16x32_bf16(afr[m][1], bfr[1][1], a1, 0, 0, 0);
            a2 = __builtin_amdgcn_mfma_f32_16x16x32_bf16(afr[m][0], bfr[2][0], a2, 0, 0, 0);
            a2 = __builtin_amdgcn_mfma_f32_16x16x32_bf16(afr[m][1], bfr[2][1], a2, 0, 0, 0);

            // window fold: out[l,d] = sum_j ki_j[l,d] * x[l-1+j,d]
            float xv[6];
            #pragma unroll
            for (int i = 0; i < 6; ++i) {
                const int row = l0 - 1 + m * 16 + g * 4 + i;
                xv[i] = ((unsigned)row < (unsigned)L_) ? xcol[(size_t)row * D_] : 0.f;
            }
            #pragma unroll
            for (int r = 0; r < 4; ++r) {
                const float o = a0[r] * xv[r] + a1[r] * xv[r + 1] + a2[r] * xv[r + 2];
                out[outBase + (size_t)(m * 16 + g * 4 + r) * D_ + dcol] = o;
            }
        }
    }
}

// ---------------------------------------------------------------------------
extern "C" void kernel_launch(void* const* d_in, const int* in_sizes, int n_in,
                              void* d_out, int out_size, void* d_ws, size_t ws_size,
                              hipStream_t stream) {
    const float* x    = (const float*)d_in[0];
    const float* C    = (const float*)d_in[1];
    const float* Wden = (const float*)d_in[2];
    const float* bden = (const float*)d_in[3];
    float* out = (float*)d_out;

    short* kcPk  = (short*)d_ws;                   // [768][64] bf16 = 98304 B
    short* CbfPk = (short*)d_ws + KW * D_ * T_;    // [64][256] bf16 = 32768 B

    cbf_kernel<<<dim3(16), dim3(256), 0, stream>>>(C, CbfPk);
    kc_prep<<<dim3(48), dim3(256), 0, stream>>>(C, Wden, bden, kcPk);

    dim3 grid(L_ / 64, B_);
    main_kernel<<<grid, dim3(256), 0, stream>>>(x, CbfPk, kcPk, out);
}

// Round 5
// 65.185 us; speedup vs baseline: 1.4859x; 1.4859x over previous
//
#include <hip/hip_runtime.h>

// Problem constants
#define B_  32
#define L_  2048
#define D_  256
#define T_  64
#define KW  3
#define ROWS  32          // rows per block
#define XROWS 34          // rows + 2 halo

typedef float f32x4 __attribute__((ext_vector_type(4)));
typedef short s16x8 __attribute__((ext_vector_type(8)));
typedef short s16x4 __attribute__((ext_vector_type(4)));

__device__ __forceinline__ short f2bf(float f) {
    unsigned u = __builtin_bit_cast(unsigned, f);
    u += 0x7FFFu + ((u >> 16) & 1u);          // round-to-nearest-even
    return (short)(u >> 16);
}
__device__ __forceinline__ float bf2f(short s) {
    unsigned u = ((unsigned)(unsigned short)s) << 16;
    return __builtin_bit_cast(float, u);
}

// ---------------------------------------------------------------------------
// prep A: CbfPk = bf16(C) packed in phase-1 B-fragment order:
//   C[t][d] -> CbfPk[(((tt*8+ks)*4+g)*16 + c)*8 + e]
//   tt=t>>4, c=t&15, ks=d>>5, g=(d>>3)&3, e=d&7
// ---------------------------------------------------------------------------
__global__ __launch_bounds__(256) void cbf_kernel(const float* __restrict__ C,
                                                  short* __restrict__ CbfPk) {
    const int i0 = (blockIdx.x * 256 + threadIdx.x) * 4;
    const int t = i0 >> 8, d = i0 & 255;
    const f32x4 v = *(const f32x4*)(C + i0);
    s16x4 s;
    s[0] = f2bf(v[0]); s[1] = f2bf(v[1]); s[2] = f2bf(v[2]); s[3] = f2bf(v[3]);
    const int tt = t >> 4, c = t & 15, ks = d >> 5, gg = (d >> 3) & 3, e = d & 7;
    *(s16x4*)&CbfPk[(((tt * 8 + ks) * 4 + gg) * 16 + c) * 8 + e] = s;
}

// ---------------------------------------------------------------------------
// prep B: kc[n][t] = relu(b[n] + sum_dd C[t][dd]*W[dd][n]) packed in phase-2
// B-fragment order: (n,t) -> kcPk[(((nb*2+ks)*4+g)*16 + c)*8 + e]
//   nb=n>>4, c=n&15, ks=t>>5, g=(t>>3)&3, e=t&7
// ---------------------------------------------------------------------------
__global__ __launch_bounds__(256) void kc_prep(const float* __restrict__ C,
                                               const float* __restrict__ W,
                                               const float* __restrict__ bias,
                                               short* __restrict__ kcPk) {
    __shared__ float Ws[256 * 16];
    const int tid = threadIdx.x;
    const int n0  = blockIdx.x * 16;

    for (int idx = tid; idx < 256 * 16; idx += 256) {
        const int dd = idx >> 4, nl = idx & 15;
        Ws[idx] = W[dd * (KW * D_) + n0 + nl];
    }
    __syncthreads();

    const int t  = tid >> 2;
    const int nl = tid & 3;
    float acc[4];
    #pragma unroll
    for (int i = 0; i < 4; ++i) acc[i] = bias[n0 + nl + 4 * i];

    const float* Crow = C + t * D_;
    for (int dd = 0; dd < D_; ++dd) {
        const float cv = Crow[dd];
        #pragma unroll
        for (int i = 0; i < 4; ++i)
            acc[i] = fmaf(cv, Ws[dd * 16 + nl + 4 * i], acc[i]);
    }
    const int nb = blockIdx.x, ks = t >> 5, gg = (t >> 3) & 3, e = t & 7;
    #pragma unroll
    for (int i = 0; i < 4; ++i) {
        const int cc = nl + 4 * i;
        kcPk[(((nb * 2 + ks) * 4 + gg) * 16 + cc) * 8 + e] = f2bf(fmaxf(acc[i], 0.f));
    }
}

// ---------------------------------------------------------------------------
// main: per block = 32 rows of one batch, 4 waves, LDS = 22.6 KB
//  (x-tile staged ONCE -> ideal HBM traffic; 7 blocks/CU -> high occupancy).
//  phase1: att[32][64] via MFMA; wave w owns t-tile w, loops 2 M-tiles.
//  phase2: wave w owns d in [w*64, w*64+64); A=atts LDS, B=kcPk packed;
//          3-tap window fold from xs LDS; fp32 store.
// ---------------------------------------------------------------------------
#define XST 264
#define ATS 72

__global__ __launch_bounds__(256, 6) void main_kernel(const float* __restrict__ x,
                                                      const short* __restrict__ CbfPk,
                                                      const short* __restrict__ kcPk,
                                                      float* __restrict__ out) {
    __shared__ short xs[XROWS * XST];      // 17952 B
    __shared__ short atts[ROWS * ATS];     //  4608 B

    const int tid  = threadIdx.x;
    const int w    = tid >> 6;        // wave 0..3
    const int lane = tid & 63;
    const int c    = lane & 15;
    const int g    = lane >> 4;
    const int l0   = blockIdx.x * ROWS;
    const int b    = blockIdx.y;

    // ---- stage x rows l0-1 .. l0+32 as bf16 (coalesced, once) ----
    const f32x4* x4 = (const f32x4*)(x + (size_t)b * L_ * D_);
    for (int idx = tid; idx < XROWS * 64; idx += 256) {
        const int row = idx >> 6;
        const int d4  = idx & 63;
        const int l   = l0 - 1 + row;
        f32x4 v = {0.f, 0.f, 0.f, 0.f};
        if (l >= 0 && l < L_) v = x4[(size_t)l * 64 + d4];
        s16x4 s;
        s[0] = f2bf(v[0]); s[1] = f2bf(v[1]); s[2] = f2bf(v[2]); s[3] = f2bf(v[3]);
        *(s16x4*)&xs[row * XST + d4 * 4] = s;
    }
    __syncthreads();

    // ---- phase 1: wave w computes all 32 rows x t-tile w ----
    {
        f32x4 acc[2];
        acc[0] = (f32x4){0.f, 0.f, 0.f, 0.f};
        acc[1] = (f32x4){0.f, 0.f, 0.f, 0.f};

        #pragma unroll
        for (int ks = 0; ks < 8; ++ks) {
            const s16x8 bf = *(const s16x8*)&CbfPk[(((w * 8 + ks) * 4 + g) * 16 + c) * 8];
            #pragma unroll
            for (int m = 0; m < 2; ++m) {
                const s16x8 a = *(const s16x8*)&xs[(1 + m * 16 + c) * XST + ks * 32 + g * 8];
                acc[m] = __builtin_amdgcn_mfma_f32_16x16x32_bf16(a, bf, acc[m], 0, 0, 0);
            }
        }
        // D layout: col=lane&15 (t), row=(lane>>4)*4+reg (l)
        #pragma unroll
        for (int m = 0; m < 2; ++m)
            #pragma unroll
            for (int r = 0; r < 4; ++r)
                atts[(m * 16 + g * 4 + r) * ATS + w * 16 + c] = f2bf(acc[m][r]);
    }
    __syncthreads();

    // ---- phase 2 ----
    s16x8 afr[2][2];
    #pragma unroll
    for (int m = 0; m < 2; ++m)
        #pragma unroll
        for (int ks = 0; ks < 2; ++ks)
            afr[m][ks] = *(const s16x8*)&atts[(m * 16 + c) * ATS + ks * 32 + g * 8];

    const size_t outBase = ((size_t)b * L_ + l0) * D_;

    #pragma unroll
    for (int dtl = 0; dtl < 4; ++dtl) {
        const int dcol    = w * 64 + dtl * 16 + c;
        const int nb_base = w * 4 + dtl;          // nb = j*16 + nb_base
        s16x8 bfr[3][2];
        #pragma unroll
        for (int j = 0; j < 3; ++j)
            #pragma unroll
            for (int ks = 0; ks < 2; ++ks)
                bfr[j][ks] = *(const s16x8*)&kcPk[((((j * 16 + nb_base) * 2 + ks) * 4 + g) * 16 + c) * 8];

        #pragma unroll
        for (int m = 0; m < 2; ++m) {
            f32x4 a0 = (f32x4){0.f,0.f,0.f,0.f};
            f32x4 a1 = (f32x4){0.f,0.f,0.f,0.f};
            f32x4 a2 = (f32x4){0.f,0.f,0.f,0.f};
            a0 = __builtin_amdgcn_mfma_f32_16x16x32_bf16(afr[m][0], bfr[0][0], a0, 0, 0, 0);
            a0 = __builtin_amdgcn_mfma_f32_16x16x32_bf16(afr[m][1], bfr[0][1], a0, 0, 0, 0);
            a1 = __builtin_amdgcn_mfma_f32_16x16x32_bf16(afr[m][0], bfr[1][0], a1, 0, 0, 0);
            a1 = __builtin_amdgcn_mfma_f32_16x16x32_bf16(afr[m][1], bfr[1][1], a1, 0, 0, 0);
            a2 = __builtin_amdgcn_mfma_f32_16x16x32_bf16(afr[m][0], bfr[2][0], a2, 0, 0, 0);
            a2 = __builtin_amdgcn_mfma_f32_16x16x32_bf16(afr[m][1], bfr[2][1], a2, 0, 0, 0);

            // window fold: out[l,d] = sum_j ki_j[l,d] * x[l-1+j,d]
            // xs row 0 == l0-1, so xs row (m*16+g*4+r+i) == x[l-1+i]
            float xv[6];
            #pragma unroll
            for (int i = 0; i < 6; ++i)
                xv[i] = bf2f(xs[(m * 16 + g * 4 + i) * XST + dcol]);

            #pragma unroll
            for (int r = 0; r < 4; ++r) {
                const float o = a0[r] * xv[r] + a1[r] * xv[r + 1] + a2[r] * xv[r + 2];
                out[outBase + (size_t)(m * 16 + g * 4 + r) * D_ + dcol] = o;
            }
        }
    }
}

// ---------------------------------------------------------------------------
extern "C" void kernel_launch(void* const* d_in, const int* in_sizes, int n_in,
                              void* d_out, int out_size, void* d_ws, size_t ws_size,
                              hipStream_t stream) {
    const float* x    = (const float*)d_in[0];
    const float* C    = (const float*)d_in[1];
    const float* Wden = (const float*)d_in[2];
    const float* bden = (const float*)d_in[3];
    float* out = (float*)d_out;

    short* kcPk  = (short*)d_ws;                   // [768][64] bf16 = 98304 B
    short* CbfPk = (short*)d_ws + KW * D_ * T_;    // [64][256] bf16 = 32768 B

    cbf_kernel<<<dim3(16), dim3(256), 0, stream>>>(C, CbfPk);
    kc_prep<<<dim3(48), dim3(256), 0, stream>>>(C, Wden, bden, kcPk);

    dim3 grid(L_ / ROWS, B_);
    main_kernel<<<grid, dim3(256), 0, stream>>>(x, CbfPk, kcPk, out);
}

// Round 6
// 52.397 us; speedup vs baseline: 1.8486x; 1.2441x over previous
//
#include <hip/hip_runtime.h>

// Problem constants
#define B_  32
#define L_  2048
#define D_  256
#define T_  64
#define KW  3
#define ROWS  16          // rows per block
#define XROWS 18          // rows + 2 halo

typedef float f32x4 __attribute__((ext_vector_type(4)));
typedef short s16x8 __attribute__((ext_vector_type(8)));
typedef short s16x4 __attribute__((ext_vector_type(4)));

__device__ __forceinline__ short f2bf(float f) {
    unsigned u = __builtin_bit_cast(unsigned, f);
    u += 0x7FFFu + ((u >> 16) & 1u);          // round-to-nearest-even
    return (short)(u >> 16);
}
__device__ __forceinline__ float bf2f(short s) {
    unsigned u = ((unsigned)(unsigned short)s) << 16;
    return __builtin_bit_cast(float, u);
}

// ---------------------------------------------------------------------------
// fused prep (one launch):
//  bx <  16 : CbfPk = bf16(C) packed in phase-1 B-fragment order
//             C[t][d] -> CbfPk[(((tt*8+ks)*4+g)*16+c)*8+e]
//  bx >= 16 : kc[n][t] = relu(b[n] + sum_dd C[t][dd]*W[dd][n]) packed in
//             phase-2 B-frag order: (n,t) -> kcPk[(((nb*2+ks)*4+g)*16+c)*8+e]
// ---------------------------------------------------------------------------
__global__ __launch_bounds__(256) void prep_kernel(const float* __restrict__ C,
                                                   const float* __restrict__ W,
                                                   const float* __restrict__ bias,
                                                   short* __restrict__ CbfPk,
                                                   short* __restrict__ kcPk) {
    __shared__ float Ws[256 * 16];
    const int tid = threadIdx.x;

    if (blockIdx.x < 16) {
        const int i0 = (blockIdx.x * 256 + tid) * 4;
        const int t = i0 >> 8, d = i0 & 255;
        const f32x4 v = *(const f32x4*)(C + i0);
        s16x4 s;
        s[0] = f2bf(v[0]); s[1] = f2bf(v[1]); s[2] = f2bf(v[2]); s[3] = f2bf(v[3]);
        const int tt = t >> 4, c = t & 15, ks = d >> 5, gg = (d >> 3) & 3, e = d & 7;
        *(s16x4*)&CbfPk[(((tt * 8 + ks) * 4 + gg) * 16 + c) * 8 + e] = s;
        return;
    }

    const int nb = blockIdx.x - 16;
    const int n0 = nb * 16;

    for (int idx = tid; idx < 256 * 16; idx += 256) {
        const int dd = idx >> 4, nl = idx & 15;
        Ws[idx] = W[dd * (KW * D_) + n0 + nl];
    }
    __syncthreads();

    const int t  = tid >> 2;
    const int nl = tid & 3;
    float acc[4];
    #pragma unroll
    for (int i = 0; i < 4; ++i) acc[i] = bias[n0 + nl + 4 * i];

    const float* Crow = C + t * D_;
    for (int dd = 0; dd < D_; ++dd) {
        const float cv = Crow[dd];
        #pragma unroll
        for (int i = 0; i < 4; ++i)
            acc[i] = fmaf(cv, Ws[dd * 16 + nl + 4 * i], acc[i]);
    }
    const int ks = t >> 5, gg = (t >> 3) & 3, e = t & 7;
    #pragma unroll
    for (int i = 0; i < 4; ++i) {
        const int cc = nl + 4 * i;
        kcPk[(((nb * 2 + ks) * 4 + gg) * 16 + cc) * 8 + e] = f2bf(fmaxf(acc[i], 0.f));
    }
}

// ---------------------------------------------------------------------------
// main: per block = 16 rows of one batch, 4 waves, LDS ~11.8 KB ->
//  8 blocks/CU (32 waves = HW max). x-tile staged once (ideal HBM traffic).
//  phase1: att[16][64] via MFMA; wave w owns t-tile w.
//  phase2: wave w owns d in [w*64, w*64+64); A=atts LDS, B=kcPk packed;
//          3-tap window fold from xs LDS; fp32 store.
// ---------------------------------------------------------------------------
#define XST 264
#define ATS 72

__global__ __launch_bounds__(256, 8) void main_kernel(const float* __restrict__ x,
                                                      const short* __restrict__ CbfPk,
                                                      const short* __restrict__ kcPk,
                                                      float* __restrict__ out) {
    __shared__ short xs[XROWS * XST];      // 9504 B
    __shared__ short atts[ROWS * ATS];     // 2304 B

    const int tid  = threadIdx.x;
    const int w    = tid >> 6;        // wave 0..3
    const int lane = tid & 63;
    const int c    = lane & 15;
    const int g    = lane >> 4;
    const int l0   = blockIdx.x * ROWS;
    const int b    = blockIdx.y;

    // ---- stage x rows l0-1 .. l0+16 as bf16 (coalesced, once) ----
    const f32x4* x4 = (const f32x4*)(x + (size_t)b * L_ * D_);
    for (int idx = tid; idx < XROWS * 64; idx += 256) {
        const int row = idx >> 6;
        const int d4  = idx & 63;
        const int l   = l0 - 1 + row;
        f32x4 v = {0.f, 0.f, 0.f, 0.f};
        if (l >= 0 && l < L_) v = x4[(size_t)l * 64 + d4];
        s16x4 s;
        s[0] = f2bf(v[0]); s[1] = f2bf(v[1]); s[2] = f2bf(v[2]); s[3] = f2bf(v[3]);
        *(s16x4*)&xs[row * XST + d4 * 4] = s;
    }
    __syncthreads();

    // ---- phase 1: wave w computes all 16 rows x t-tile w ----
    {
        f32x4 acc = (f32x4){0.f, 0.f, 0.f, 0.f};
        #pragma unroll
        for (int ks = 0; ks < 8; ++ks) {
            const s16x8 bf = *(const s16x8*)&CbfPk[(((w * 8 + ks) * 4 + g) * 16 + c) * 8];
            const s16x8 a  = *(const s16x8*)&xs[(1 + c) * XST + ks * 32 + g * 8];
            acc = __builtin_amdgcn_mfma_f32_16x16x32_bf16(a, bf, acc, 0, 0, 0);
        }
        // D layout: col=lane&15 (t), row=(lane>>4)*4+reg (l)
        #pragma unroll
        for (int r = 0; r < 4; ++r)
            atts[(g * 4 + r) * ATS + w * 16 + c] = f2bf(acc[r]);
    }
    __syncthreads();

    // ---- phase 2 ----
    s16x8 afr[2];
    #pragma unroll
    for (int ks = 0; ks < 2; ++ks)
        afr[ks] = *(const s16x8*)&atts[c * ATS + ks * 32 + g * 8];

    const size_t outBase = ((size_t)b * L_ + l0) * D_;

    #pragma unroll
    for (int dtl = 0; dtl < 4; ++dtl) {
        const int dcol    = w * 64 + dtl * 16 + c;
        const int nb_base = w * 4 + dtl;          // nb = j*16 + nb_base
        s16x8 bfr[3][2];
        #pragma unroll
        for (int j = 0; j < 3; ++j)
            #pragma unroll
            for (int ks = 0; ks < 2; ++ks)
                bfr[j][ks] = *(const s16x8*)&kcPk[((((j * 16 + nb_base) * 2 + ks) * 4 + g) * 16 + c) * 8];

        f32x4 a0 = (f32x4){0.f,0.f,0.f,0.f};
        f32x4 a1 = (f32x4){0.f,0.f,0.f,0.f};
        f32x4 a2 = (f32x4){0.f,0.f,0.f,0.f};
        a0 = __builtin_amdgcn_mfma_f32_16x16x32_bf16(afr[0], bfr[0][0], a0, 0, 0, 0);
        a0 = __builtin_amdgcn_mfma_f32_16x16x32_bf16(afr[1], bfr[0][1], a0, 0, 0, 0);
        a1 = __builtin_amdgcn_mfma_f32_16x16x32_bf16(afr[0], bfr[1][0], a1, 0, 0, 0);
        a1 = __builtin_amdgcn_mfma_f32_16x16x32_bf16(afr[1], bfr[1][1], a1, 0, 0, 0);
        a2 = __builtin_amdgcn_mfma_f32_16x16x32_bf16(afr[0], bfr[2][0], a2, 0, 0, 0);
        a2 = __builtin_amdgcn_mfma_f32_16x16x32_bf16(afr[1], bfr[2][1], a2, 0, 0, 0);

        // window fold: out[l,d] = sum_j ki_j[l,d] * x[l-1+j,d]
        // xs row 0 == l0-1, so xs row (g*4+r+i) == x[l0+g*4+r-1+i]
        float xv[6];
        #pragma unroll
        for (int i = 0; i < 6; ++i)
            xv[i] = bf2f(xs[(g * 4 + i) * XST + dcol]);

        #pragma unroll
        for (int r = 0; r < 4; ++r) {
            const float o = a0[r] * xv[r] + a1[r] * xv[r + 1] + a2[r] * xv[r + 2];
            out[outBase + (size_t)(g * 4 + r) * D_ + dcol] = o;
        }
    }
}

// ---------------------------------------------------------------------------
extern "C" void kernel_launch(void* const* d_in, const int* in_sizes, int n_in,
                              void* d_out, int out_size, void* d_ws, size_t ws_size,
                              hipStream_t stream) {
    const float* x    = (const float*)d_in[0];
    const float* C    = (const float*)d_in[1];
    const float* Wden = (const float*)d_in[2];
    const float* bden = (const float*)d_in[3];
    float* out = (float*)d_out;

    short* kcPk  = (short*)d_ws;                   // [768][64] bf16 = 98304 B
    short* CbfPk = (short*)d_ws + KW * D_ * T_;    // [64][256] bf16 = 32768 B

    prep_kernel<<<dim3(64), dim3(256), 0, stream>>>(C, Wden, bden, CbfPk, kcPk);

    dim3 grid(L_ / ROWS, B_);
    main_kernel<<<grid, dim3(256), 0, stream>>>(x, CbfPk, kcPk, out);
}

// Round 7
// 48.152 us; speedup vs baseline: 2.0116x; 1.0882x over previous
//
#include <hip/hip_runtime.h>

// Problem constants
#define B_  32
#define L_  2048
#define D_  256
#define T_  64
#define KW  3
#define ROWS  16          // rows per block
#define XROWS 18          // rows + 2 halo

typedef float f32x4 __attribute__((ext_vector_type(4)));
typedef short s16x8 __attribute__((ext_vector_type(8)));
typedef short s16x4 __attribute__((ext_vector_type(4)));

__device__ __forceinline__ short f2bf(float f) {
    unsigned u = __builtin_bit_cast(unsigned, f);
    u += 0x7FFFu + ((u >> 16) & 1u);          // round-to-nearest-even
    return (short)(u >> 16);
}
__device__ __forceinline__ float bf2f(short s) {
    unsigned u = ((unsigned)(unsigned short)s) << 16;
    return __builtin_bit_cast(float, u);
}

// ---------------------------------------------------------------------------
// fused prep (one launch):
//  bx <  16 : CbfPk = bf16(C) packed in phase-1 B-fragment order
//             C[t][d] -> CbfPk[(((tt*8+ks)*4+g)*16+c)*8+e]
//  bx >= 16 : kc[n][t] = relu(b[n] + sum_dd C[t][dd]*W[dd][n]) packed in
//             phase-2 B-frag order: (n,t) -> kcPk[(((nb*2+ks)*4+g)*16+c)*8+e]
// ---------------------------------------------------------------------------
__global__ __launch_bounds__(256) void prep_kernel(const float* __restrict__ C,
                                                   const float* __restrict__ W,
                                                   const float* __restrict__ bias,
                                                   short* __restrict__ CbfPk,
                                                   short* __restrict__ kcPk) {
    __shared__ float Ws[256 * 16];
    const int tid = threadIdx.x;

    if (blockIdx.x < 16) {
        const int i0 = (blockIdx.x * 256 + tid) * 4;
        const int t = i0 >> 8, d = i0 & 255;
        const f32x4 v = *(const f32x4*)(C + i0);
        s16x4 s;
        s[0] = f2bf(v[0]); s[1] = f2bf(v[1]); s[2] = f2bf(v[2]); s[3] = f2bf(v[3]);
        const int tt = t >> 4, c = t & 15, ks = d >> 5, gg = (d >> 3) & 3, e = d & 7;
        *(s16x4*)&CbfPk[(((tt * 8 + ks) * 4 + gg) * 16 + c) * 8 + e] = s;
        return;
    }

    const int nb = blockIdx.x - 16;
    const int n0 = nb * 16;

    for (int idx = tid; idx < 256 * 16; idx += 256) {
        const int dd = idx >> 4, nl = idx & 15;
        Ws[idx] = W[dd * (KW * D_) + n0 + nl];
    }
    __syncthreads();

    const int t  = tid >> 2;
    const int nl = tid & 3;
    float acc[4];
    #pragma unroll
    for (int i = 0; i < 4; ++i) acc[i] = bias[n0 + nl + 4 * i];

    const float* Crow = C + t * D_;
    for (int dd = 0; dd < D_; ++dd) {
        const float cv = Crow[dd];
        #pragma unroll
        for (int i = 0; i < 4; ++i)
            acc[i] = fmaf(cv, Ws[dd * 16 + nl + 4 * i], acc[i]);
    }
    const int ks = t >> 5, gg = (t >> 3) & 3, e = t & 7;
    #pragma unroll
    for (int i = 0; i < 4; ++i) {
        const int cc = nl + 4 * i;
        kcPk[(((nb * 2 + ks) * 4 + gg) * 16 + cc) * 8 + e] = f2bf(fmaxf(acc[i], 0.f));
    }
}

// ---------------------------------------------------------------------------
// main kernel helpers: phase-2 B-fragment bundle + compute step, all indices
// compile-time constant after inlining (no runtime-indexed arrays -> no
// scratch; explicit 2-deep software pipeline).
// ---------------------------------------------------------------------------
#define XST 264
#define ATS 72

struct BFrag { s16x8 v[6]; };   // [j][ks] flattened, j-major

__device__ __forceinline__ BFrag load_bfr(const short* __restrict__ kcPk,
                                          int w, int g, int c, int dtl) {
    BFrag f;
    #pragma unroll
    for (int j = 0; j < 3; ++j)
        #pragma unroll
        for (int ks = 0; ks < 2; ++ks)
            f.v[j * 2 + ks] = *(const s16x8*)
                &kcPk[((((j * 16 + w * 4 + dtl) * 2 + ks) * 4 + g) * 16 + c) * 8];
    return f;
}

__device__ __forceinline__ void compute_dtl(const BFrag& bf,
                                            s16x8 afr0, s16x8 afr1,
                                            const short* xs,
                                            float* __restrict__ out, size_t outBase,
                                            int g, int c, int w, int dtl) {
    f32x4 a0 = (f32x4){0.f,0.f,0.f,0.f};
    f32x4 a1 = (f32x4){0.f,0.f,0.f,0.f};
    f32x4 a2 = (f32x4){0.f,0.f,0.f,0.f};
    a0 = __builtin_amdgcn_mfma_f32_16x16x32_bf16(afr0, bf.v[0], a0, 0, 0, 0);
    a0 = __builtin_amdgcn_mfma_f32_16x16x32_bf16(afr1, bf.v[1], a0, 0, 0, 0);
    a1 = __builtin_amdgcn_mfma_f32_16x16x32_bf16(afr0, bf.v[2], a1, 0, 0, 0);
    a1 = __builtin_amdgcn_mfma_f32_16x16x32_bf16(afr1, bf.v[3], a1, 0, 0, 0);
    a2 = __builtin_amdgcn_mfma_f32_16x16x32_bf16(afr0, bf.v[4], a2, 0, 0, 0);
    a2 = __builtin_amdgcn_mfma_f32_16x16x32_bf16(afr1, bf.v[5], a2, 0, 0, 0);

    const int dcol = w * 64 + dtl * 16 + c;
    // window fold: out[l,d] = sum_j ki_j[l,d] * x[l-1+j,d]; xs row 0 == l0-1
    float xv[6];
    #pragma unroll
    for (int i = 0; i < 6; ++i)
        xv[i] = bf2f(xs[(g * 4 + i) * XST + dcol]);

    #pragma unroll
    for (int r = 0; r < 4; ++r) {
        const float o = a0[r] * xv[r] + a1[r] * xv[r + 1] + a2[r] * xv[r + 2];
        out[outBase + (size_t)(g * 4 + r) * D_ + dcol] = o;
    }
}

// ---------------------------------------------------------------------------
// main: per block = 16 rows of one batch, 4 waves, LDS ~11.8 KB.
//  - C-frags prefetched at kernel start (L2 latency hides under x staging)
//  - phase-2 B-frags 2-deep software-pipelined; dtl=0 prefetched pre-barrier
// ---------------------------------------------------------------------------
__global__ __launch_bounds__(256, 6) void main_kernel(const float* __restrict__ x,
                                                      const short* __restrict__ CbfPk,
                                                      const short* __restrict__ kcPk,
                                                      float* __restrict__ out) {
    __shared__ short xs[XROWS * XST];      // 9504 B
    __shared__ short atts[ROWS * ATS];     // 2304 B

    const int tid  = threadIdx.x;
    const int w    = tid >> 6;        // wave 0..3
    const int lane = tid & 63;
    const int c    = lane & 15;
    const int g    = lane >> 4;
    const int l0   = blockIdx.x * ROWS;
    const int b    = blockIdx.y;

    // ---- prefetch phase-1 B fragments (independent of staging) ----
    s16x8 cb0 = *(const s16x8*)&CbfPk[(((w * 8 + 0) * 4 + g) * 16 + c) * 8];
    s16x8 cb1 = *(const s16x8*)&CbfPk[(((w * 8 + 1) * 4 + g) * 16 + c) * 8];
    s16x8 cb2 = *(const s16x8*)&CbfPk[(((w * 8 + 2) * 4 + g) * 16 + c) * 8];
    s16x8 cb3 = *(const s16x8*)&CbfPk[(((w * 8 + 3) * 4 + g) * 16 + c) * 8];
    s16x8 cb4 = *(const s16x8*)&CbfPk[(((w * 8 + 4) * 4 + g) * 16 + c) * 8];
    s16x8 cb5 = *(const s16x8*)&CbfPk[(((w * 8 + 5) * 4 + g) * 16 + c) * 8];
    s16x8 cb6 = *(const s16x8*)&CbfPk[(((w * 8 + 6) * 4 + g) * 16 + c) * 8];
    s16x8 cb7 = *(const s16x8*)&CbfPk[(((w * 8 + 7) * 4 + g) * 16 + c) * 8];

    // ---- stage x rows l0-1 .. l0+16 as bf16 (coalesced, once) ----
    const f32x4* x4 = (const f32x4*)(x + (size_t)b * L_ * D_);
    for (int idx = tid; idx < XROWS * 64; idx += 256) {
        const int row = idx >> 6;
        const int d4  = idx & 63;
        const int l   = l0 - 1 + row;
        f32x4 v = {0.f, 0.f, 0.f, 0.f};
        if (l >= 0 && l < L_) v = x4[(size_t)l * 64 + d4];
        s16x4 s;
        s[0] = f2bf(v[0]); s[1] = f2bf(v[1]); s[2] = f2bf(v[2]); s[3] = f2bf(v[3]);
        *(s16x4*)&xs[row * XST + d4 * 4] = s;
    }
    __syncthreads();

    // ---- phase 1: wave w computes all 16 rows x t-tile w ----
    {
        f32x4 acc = (f32x4){0.f, 0.f, 0.f, 0.f};
        const short* xr = &xs[(1 + c) * XST];
        acc = __builtin_amdgcn_mfma_f32_16x16x32_bf16(*(const s16x8*)&xr[0*32 + g*8], cb0, acc, 0, 0, 0);
        acc = __builtin_amdgcn_mfma_f32_16x16x32_bf16(*(const s16x8*)&xr[1*32 + g*8], cb1, acc, 0, 0, 0);
        acc = __builtin_amdgcn_mfma_f32_16x16x32_bf16(*(const s16x8*)&xr[2*32 + g*8], cb2, acc, 0, 0, 0);
        acc = __builtin_amdgcn_mfma_f32_16x16x32_bf16(*(const s16x8*)&xr[3*32 + g*8], cb3, acc, 0, 0, 0);
        acc = __builtin_amdgcn_mfma_f32_16x16x32_bf16(*(const s16x8*)&xr[4*32 + g*8], cb4, acc, 0, 0, 0);
        acc = __builtin_amdgcn_mfma_f32_16x16x32_bf16(*(const s16x8*)&xr[5*32 + g*8], cb5, acc, 0, 0, 0);
        acc = __builtin_amdgcn_mfma_f32_16x16x32_bf16(*(const s16x8*)&xr[6*32 + g*8], cb6, acc, 0, 0, 0);
        acc = __builtin_amdgcn_mfma_f32_16x16x32_bf16(*(const s16x8*)&xr[7*32 + g*8], cb7, acc, 0, 0, 0);
        // D layout: col=lane&15 (t), row=(lane>>4)*4+reg (l)
        #pragma unroll
        for (int r = 0; r < 4; ++r)
            atts[(g * 4 + r) * ATS + w * 16 + c] = f2bf(acc[r]);
    }

    // ---- prefetch dtl=0 phase-2 B frags BEFORE the barrier ----
    BFrag bA = load_bfr(kcPk, w, g, c, 0);
    __syncthreads();

    // ---- phase 2: 2-deep software pipeline over the 4 d-tiles ----
    s16x8 afr0 = *(const s16x8*)&atts[c * ATS + 0 * 32 + g * 8];
    s16x8 afr1 = *(const s16x8*)&atts[c * ATS + 1 * 32 + g * 8];

    const size_t outBase = ((size_t)b * L_ + l0) * D_;

    BFrag bB = load_bfr(kcPk, w, g, c, 1);
    compute_dtl(bA, afr0, afr1, xs, out, outBase, g, c, w, 0);
    bA = load_bfr(kcPk, w, g, c, 2);
    compute_dtl(bB, afr0, afr1, xs, out, outBase, g, c, w, 1);
    bB = load_bfr(kcPk, w, g, c, 3);
    compute_dtl(bA, afr0, afr1, xs, out, outBase, g, c, w, 2);
    compute_dtl(bB, afr0, afr1, xs, out, outBase, g, c, w, 3);
}

// ---------------------------------------------------------------------------
extern "C" void kernel_launch(void* const* d_in, const int* in_sizes, int n_in,
                              void* d_out, int out_size, void* d_ws, size_t ws_size,
                              hipStream_t stream) {
    const float* x    = (const float*)d_in[0];
    const float* C    = (const float*)d_in[1];
    const float* Wden = (const float*)d_in[2];
    const float* bden = (const float*)d_in[3];
    float* out = (float*)d_out;

    short* kcPk  = (short*)d_ws;                   // [768][64] bf16 = 98304 B
    short* CbfPk = (short*)d_ws + KW * D_ * T_;    // [64][256] bf16 = 32768 B

    prep_kernel<<<dim3(64), dim3(256), 0, stream>>>(C, Wden, bden, CbfPk, kcPk);

    dim3 grid(L_ / ROWS, B_);
    main_kernel<<<grid, dim3(256), 0, stream>>>(x, CbfPk, kcPk, out);
}